// Round 3
// baseline (110.727 us; speedup 1.0000x reference)
//
#include <hip/hip_runtime.h>
#include <math.h>

#define N_FFT 16384
#define ROWS 1024   // B*Cin = B*Cout = 16*64

__global__ __launch_bounds__(256) void k_tab(float* __restrict__ castab) {
    int i = blockIdx.x * 256 + threadIdx.x;
    if (i < N_FFT) {
        double ang = 6.283185307179586476925287 * (double)i / (double)N_FFT;
        castab[i] = (float)(cos(ang) + sin(ang));
    }
}

__global__ __launch_bounds__(256) void k_fill(const float* __restrict__ castab,
                                              float* __restrict__ casA,
                                              float* __restrict__ casB) {
    int tid = blockIdx.x * 256 + threadIdx.x;   // 0 .. 2*2^20-1
    if (tid < (1 << 20)) {
        int n = tid >> 6, m = tid & 63;
        casA[tid] = castab[(n * m) & (N_FFT - 1)];
    } else {
        int t2 = tid - (1 << 20);
        int m = t2 >> 14, n = t2 & (N_FFT - 1);
        casB[t2] = castab[(m * n) & (N_FFT - 1)];
    }
}

// Step A: partial[ks][r][m] = sum_{k in range} x[r][k] * casA[k][m]
// grid 8*KS; block 128 = 16 rq * 8 mq; tile 128r x 64m; per-thread 8x8.
// LDS: xs[32][136] ([k][r], transposed, pad 136 -> 2-way writes, free reads)
//      cs[32][64]  ([k][m])
__global__ __launch_bounds__(128) void kA(const float* __restrict__ x,
                                          const float* __restrict__ casA,
                                          float* __restrict__ partial,
                                          const int krange) {
    const int rb = blockIdx.x & 7;
    const int ks = blockIdx.x >> 3;
    const int rowbase = rb << 7;
    const int kbase = ks * krange;
    const int chunks = krange >> 5;   // Kc = 32

    __shared__ float xs[32][136];
    __shared__ float cs[32][64];

    const int t  = threadIdx.x;
    const int rq = t >> 3;            // rows rq*8 .. +7
    const int mq = t & 7;             // m = mq*8 .. +7

    float acc[8][8];
#pragma unroll
    for (int j = 0; j < 8; ++j)
#pragma unroll
        for (int q = 0; q < 8; ++q) acc[j][q] = 0.f;

    float4 xr[8], cr[4];

    // ---- stage chunk 0 ----
#pragma unroll
    for (int it = 0; it < 8; ++it) {
        int f = it * 128 + t, kq = f & 7, r = f >> 3;
        xr[it] = *reinterpret_cast<const float4*>(
            &x[(size_t)(rowbase + r) * N_FFT + kbase + kq * 4]);
    }
#pragma unroll
    for (int it = 0; it < 4; ++it) {
        int f = it * 128 + t;
        cr[it] = *reinterpret_cast<const float4*>(&casA[(size_t)kbase * 64 + f * 4]);
    }
#pragma unroll
    for (int it = 0; it < 8; ++it) {
        int f = it * 128 + t, kq = f & 7, r = f >> 3;
        xs[kq * 4 + 0][r] = xr[it].x;
        xs[kq * 4 + 1][r] = xr[it].y;
        xs[kq * 4 + 2][r] = xr[it].z;
        xs[kq * 4 + 3][r] = xr[it].w;
    }
#pragma unroll
    for (int it = 0; it < 4; ++it) {
        int f = it * 128 + t;
        *reinterpret_cast<float4*>(&cs[f >> 4][(f & 15) * 4]) = cr[it];
    }
    __syncthreads();

    for (int c = 0; c < chunks; ++c) {
        // prefetch next chunk into regs (latency hides under compute)
        if (c + 1 < chunks) {
            const int k0 = kbase + (c + 1) * 32;
#pragma unroll
            for (int it = 0; it < 8; ++it) {
                int f = it * 128 + t, kq = f & 7, r = f >> 3;
                xr[it] = *reinterpret_cast<const float4*>(
                    &x[(size_t)(rowbase + r) * N_FFT + k0 + kq * 4]);
            }
#pragma unroll
            for (int it = 0; it < 4; ++it) {
                int f = it * 128 + t;
                cr[it] = *reinterpret_cast<const float4*>(&casA[(size_t)k0 * 64 + f * 4]);
            }
        }
        // compute current chunk
#pragma unroll 4
        for (int k = 0; k < 32; ++k) {
            const float4 a0 = *reinterpret_cast<const float4*>(&xs[k][rq * 8]);
            const float4 a1 = *reinterpret_cast<const float4*>(&xs[k][rq * 8 + 4]);
            const float4 c0 = *reinterpret_cast<const float4*>(&cs[k][mq * 8]);
            const float4 c1 = *reinterpret_cast<const float4*>(&cs[k][mq * 8 + 4]);
            const float av[8] = {a0.x, a0.y, a0.z, a0.w, a1.x, a1.y, a1.z, a1.w};
            const float cv[8] = {c0.x, c0.y, c0.z, c0.w, c1.x, c1.y, c1.z, c1.w};
#pragma unroll
            for (int j = 0; j < 8; ++j)
#pragma unroll
                for (int q = 0; q < 8; ++q)
                    acc[j][q] = fmaf(av[j], cv[q], acc[j][q]);
        }
        __syncthreads();
        if (c + 1 < chunks) {
#pragma unroll
            for (int it = 0; it < 8; ++it) {
                int f = it * 128 + t, kq = f & 7, r = f >> 3;
                xs[kq * 4 + 0][r] = xr[it].x;
                xs[kq * 4 + 1][r] = xr[it].y;
                xs[kq * 4 + 2][r] = xr[it].z;
                xs[kq * 4 + 3][r] = xr[it].w;
            }
#pragma unroll
            for (int it = 0; it < 4; ++it) {
                int f = it * 128 + t;
                *reinterpret_cast<float4*>(&cs[f >> 4][(f & 15) * 4]) = cr[it];
            }
            __syncthreads();
        }
    }

#pragma unroll
    for (int j = 0; j < 8; ++j) {
        float* p = &partial[((size_t)ks * ROWS + rowbase + rq * 8 + j) * 64 + mq * 8];
        *reinterpret_cast<float4*>(p)     = make_float4(acc[j][0], acc[j][1], acc[j][2], acc[j][3]);
        *reinterpret_cast<float4*>(p + 4) = make_float4(acc[j][4], acc[j][5], acc[j][6], acc[j][7]);
    }
}

// reduce KS partials -> xh; grid 256 x 256
__global__ __launch_bounds__(256) void kR(const float* __restrict__ partial,
                                          float* __restrict__ xh, const int KS) {
    const int idx = blockIdx.x * 256 + threadIdx.x;   // 0..65535
    float a0 = 0.f, a1 = 0.f, a2 = 0.f, a3 = 0.f;
    for (int sp = 0; sp < KS; sp += 4) {
        a0 += partial[((size_t)(sp + 0) << 16) + idx];
        a1 += partial[((size_t)(sp + 1) << 16) + idx];
        a2 += partial[((size_t)(sp + 2) << 16) + idx];
        a3 += partial[((size_t)(sp + 3) << 16) + idx];
    }
    xh[idx] = (a0 + a1) + (a2 + a3);
}

// Step B: lowT[m][b*64+o] = (1/N) * sum_i xh[b*64+i][m] * w[(o*64+i)*64+m]
__global__ __launch_bounds__(256) void kB(const float* __restrict__ xh,
                                          const float* __restrict__ w,
                                          float* __restrict__ lowT) {
    const int b  = blockIdx.x >> 4;
    const int og = blockIdx.x & 15;
    const int o  = og * 4 + (threadIdx.x >> 6);
    const int m  = threadIdx.x & 63;
    float a0 = 0.f, a1 = 0.f, a2 = 0.f, a3 = 0.f;
#pragma unroll 4
    for (int i = 0; i < 64; i += 4) {
        a0 = fmaf(xh[(size_t)((b * 64 + i + 0) << 6) + m], w[(size_t)((o * 64 + i + 0) << 6) + m], a0);
        a1 = fmaf(xh[(size_t)((b * 64 + i + 1) << 6) + m], w[(size_t)((o * 64 + i + 1) << 6) + m], a1);
        a2 = fmaf(xh[(size_t)((b * 64 + i + 2) << 6) + m], w[(size_t)((o * 64 + i + 2) << 6) + m], a2);
        a3 = fmaf(xh[(size_t)((b * 64 + i + 3) << 6) + m], w[(size_t)((o * 64 + i + 3) << 6) + m], a3);
    }
    lowT[(size_t)m * ROWS + b * 64 + o] = ((a0 + a1) + (a2 + a3)) * (1.0f / (float)N_FFT);
}

// Step C: out[r][n] = sum_m lowT[m][r] * casB[m][n]
// grid 1024 = 8 rb * 128 nb; block 256 = 16 rg * 16 ng; tile 128r x 128n;
// per-thread 8r x (ng*4..+3, 64+ng*4..+3). Staged once (K=64), LDS 64 KB.
__global__ __launch_bounds__(256) void kC(const float* __restrict__ lowT,
                                          const float* __restrict__ casB,
                                          float* __restrict__ out) {
    const int nb = blockIdx.x & 127;
    const int rb = blockIdx.x >> 7;
    const int rowbase = rb << 7;
    const int n0 = nb << 7;

    __shared__ float lsd[64][128];    // [m][r]
    __shared__ float csb[64][128];    // [m][n]

    const int t  = threadIdx.x;
    const int rg = t >> 4;            // rows rg*8 .. +7
    const int ng = t & 15;

#pragma unroll
    for (int it = 0; it < 8; ++it) {
        int f = it * 256 + t;         // 0..2047 float4 tiles
        int m = f >> 5, u = f & 31;
        *reinterpret_cast<float4*>(&lsd[m][u * 4]) =
            *reinterpret_cast<const float4*>(&lowT[(size_t)m * ROWS + rowbase + u * 4]);
        *reinterpret_cast<float4*>(&csb[m][u * 4]) =
            *reinterpret_cast<const float4*>(&casB[(size_t)m * N_FFT + n0 + u * 4]);
    }
    __syncthreads();

    float acc[8][8];
#pragma unroll
    for (int j = 0; j < 8; ++j)
#pragma unroll
        for (int q = 0; q < 8; ++q) acc[j][q] = 0.f;

#pragma unroll 4
    for (int k = 0; k < 64; ++k) {
        const float4 l0 = *reinterpret_cast<const float4*>(&lsd[k][rg * 8]);
        const float4 l1 = *reinterpret_cast<const float4*>(&lsd[k][rg * 8 + 4]);
        const float4 c0 = *reinterpret_cast<const float4*>(&csb[k][ng * 4]);
        const float4 c1 = *reinterpret_cast<const float4*>(&csb[k][64 + ng * 4]);
        const float lv[8] = {l0.x, l0.y, l0.z, l0.w, l1.x, l1.y, l1.z, l1.w};
        const float cv[8] = {c0.x, c0.y, c0.z, c0.w, c1.x, c1.y, c1.z, c1.w};
#pragma unroll
        for (int j = 0; j < 8; ++j)
#pragma unroll
            for (int q = 0; q < 8; ++q)
                acc[j][q] = fmaf(lv[j], cv[q], acc[j][q]);
    }

#pragma unroll
    for (int j = 0; j < 8; ++j) {
        const size_t row = (size_t)rowbase + rg * 8 + j;
        *reinterpret_cast<float4*>(&out[row * N_FFT + n0 + ng * 4]) =
            make_float4(acc[j][0], acc[j][1], acc[j][2], acc[j][3]);
        *reinterpret_cast<float4*>(&out[row * N_FFT + n0 + 64 + ng * 4]) =
            make_float4(acc[j][4], acc[j][5], acc[j][6], acc[j][7]);
    }
}

extern "C" void kernel_launch(void* const* d_in, const int* in_sizes, int n_in,
                              void* d_out, int out_size, void* d_ws, size_t ws_size,
                              hipStream_t stream) {
    const float* x = (const float*)d_in[0];
    const float* w = (const float*)d_in[1];
    float* out = (float*)d_out;
    float* ws  = (float*)d_ws;

    const size_t need128 = ((size_t)2113536 + (size_t)128 * 65536 + 2 * 65536) * 4;
    const int KS = (ws_size >= need128) ? 128 : 64;
    const int krange = N_FFT / KS;

    float* castab  = ws;
    float* casA    = ws + 16384;
    float* casB    = ws + 1064960;
    float* partial = ws + 2113536;
    float* xh      = partial + (size_t)KS * 65536;
    float* lowT    = xh + 65536;

    k_tab<<<64, 256, 0, stream>>>(castab);
    k_fill<<<8192, 256, 0, stream>>>(castab, casA, casB);
    kA<<<8 * KS, 128, 0, stream>>>(x, casA, partial, krange);
    kR<<<256, 256, 0, stream>>>(partial, xh, KS);
    kB<<<256, 256, 0, stream>>>(xh, w, lowT);
    kC<<<1024, 256, 0, stream>>>(lowT, casB, out);
}

// Round 4
// 103.135 us; speedup vs baseline: 1.0736x; 1.0736x over previous
//
#include <hip/hip_runtime.h>
#include <math.h>

#define N_FFT 16384
#define ROWS 1024   // B*Cin = B*Cout = 16*64

__global__ __launch_bounds__(256) void k_tab(float* __restrict__ castab) {
    int i = blockIdx.x * 256 + threadIdx.x;
    if (i < N_FFT) {
        double ang = 6.283185307179586476925287 * (double)i / (double)N_FFT;
        castab[i] = (float)(cos(ang) + sin(ang));
    }
}

// casA: [16384][64] castab[(n*m)&mask]; casB: [64][8192] castab[(m*n)&mask]
__global__ __launch_bounds__(256) void k_fill(const float* __restrict__ castab,
                                              float* __restrict__ casA,
                                              float* __restrict__ casB) {
    int tid = blockIdx.x * 256 + threadIdx.x;   // 0 .. 1572863
    if (tid < (1 << 20)) {
        int n = tid >> 6, m = tid & 63;
        casA[tid] = castab[(n * m) & (N_FFT - 1)];
    } else {
        int t2 = tid - (1 << 20);               // 0 .. 2^19-1
        int m = t2 >> 13, n = t2 & 8191;
        casB[t2] = castab[(m * n) & (N_FFT - 1)];
    }
}

// Step A: partial[ks][r][m] = sum_{k in split} x[r][k] * casA[k][m]
// grid 8*KS; block 128 = 16 rq * 8 mq; tile 128r x 64m; per-thread 8x8.
// x: global->registers (no LDS; dup addrs across mq merge in coalescer).
// cas: LDS, staged 32KB chunk at a time, broadcast conflict-free reads.
__global__ __launch_bounds__(128) void kA(const float* __restrict__ x,
                                          const float* __restrict__ casA,
                                          float* __restrict__ partial,
                                          const int krange) {
    const int rb = blockIdx.x & 7;
    const int ks = blockIdx.x >> 3;
    const int rowbase = rb << 7;
    const int kbase = ks * krange;

    __shared__ float cs[128 * 64];   // [n_local][m]

    const int t  = threadIdx.x;
    const int rq = t >> 3;           // rows rq*8 .. +7
    const int mq = t & 7;            // m = mq*8 .. +7

    float acc[8][8];
#pragma unroll
    for (int j = 0; j < 8; ++j)
#pragma unroll
        for (int q = 0; q < 8; ++q) acc[j][q] = 0.f;

    const size_t rowoff = (size_t)(rowbase + rq * 8) * N_FFT + kbase;

    float4 bufA[8], bufB[8];

#define PREF(BUF, NOFF)                                                         \
    _Pragma("unroll")                                                           \
    for (int j = 0; j < 8; ++j)                                                 \
        BUF[j] = *reinterpret_cast<const float4*>(                              \
            &x[rowoff + (size_t)j * N_FFT + (NOFF)]);

#define COMP(BUF, NLOC)                                                         \
    _Pragma("unroll")                                                           \
    for (int u = 0; u < 4; ++u) {                                               \
        const float4 c0 = *reinterpret_cast<const float4*>(                     \
            &cs[((NLOC) + u) * 64 + mq * 8]);                                   \
        const float4 c1 = *reinterpret_cast<const float4*>(                     \
            &cs[((NLOC) + u) * 64 + mq * 8 + 4]);                               \
        const float cv[8] = {c0.x, c0.y, c0.z, c0.w, c1.x, c1.y, c1.z, c1.w};   \
        _Pragma("unroll")                                                       \
        for (int j = 0; j < 8; ++j) {                                           \
            const float a = reinterpret_cast<const float*>(&BUF[j])[u];         \
            _Pragma("unroll")                                                   \
            for (int q = 0; q < 8; ++q)                                         \
                acc[j][q] = fmaf(a, cv[q], acc[j][q]);                          \
        }                                                                       \
    }

    for (int c = 0; c < krange; c += 128) {
        __syncthreads();
        // stage 128n x 64m = 8192 floats of casA (contiguous)
        const float4* src = reinterpret_cast<const float4*>(&casA[(size_t)(kbase + c) * 64]);
        float4* dst = reinterpret_cast<float4*>(cs);
#pragma unroll
        for (int it = 0; it < 16; ++it) dst[it * 128 + t] = src[it * 128 + t];
        __syncthreads();

        PREF(bufA, c);
        for (int gg = 0; gg < 16; ++gg) {
            const int nl = gg * 8;                 // local n of bufA granule
            PREF(bufB, c + nl + 4);
            COMP(bufA, nl);
            if (gg < 15) { PREF(bufA, c + nl + 8); }
            COMP(bufB, nl + 4);
        }
    }
#undef PREF
#undef COMP

#pragma unroll
    for (int j = 0; j < 8; ++j) {
        float* p = &partial[((size_t)ks << 16) + (size_t)(rowbase + rq * 8 + j) * 64 + mq * 8];
        *reinterpret_cast<float4*>(p)     = make_float4(acc[j][0], acc[j][1], acc[j][2], acc[j][3]);
        *reinterpret_cast<float4*>(p + 4) = make_float4(acc[j][4], acc[j][5], acc[j][6], acc[j][7]);
    }
}

// reduce KS partials -> xh; grid 256 x 256
__global__ __launch_bounds__(256) void kR(const float* __restrict__ partial,
                                          float* __restrict__ xh, const int KS) {
    const int idx = blockIdx.x * 256 + threadIdx.x;   // 0..65535
    float a0 = 0.f, a1 = 0.f, a2 = 0.f, a3 = 0.f;
    for (int sp = 0; sp < KS; sp += 4) {
        a0 += partial[((size_t)(sp + 0) << 16) + idx];
        a1 += partial[((size_t)(sp + 1) << 16) + idx];
        a2 += partial[((size_t)(sp + 2) << 16) + idx];
        a3 += partial[((size_t)(sp + 3) << 16) + idx];
    }
    xh[idx] = (a0 + a1) + (a2 + a3);
}

// Step B: lowT[m][b*64+o] = (1/N) * sum_i xh[b*64+i][m] * w[(o*64+i)*64+m]
__global__ __launch_bounds__(256) void kB(const float* __restrict__ xh,
                                          const float* __restrict__ w,
                                          float* __restrict__ lowT) {
    const int b  = blockIdx.x >> 4;
    const int og = blockIdx.x & 15;
    const int o  = og * 4 + (threadIdx.x >> 6);
    const int m  = threadIdx.x & 63;
    float a0 = 0.f, a1 = 0.f, a2 = 0.f, a3 = 0.f;
#pragma unroll 4
    for (int i = 0; i < 64; i += 4) {
        a0 = fmaf(xh[(size_t)((b * 64 + i + 0) << 6) + m], w[(size_t)((o * 64 + i + 0) << 6) + m], a0);
        a1 = fmaf(xh[(size_t)((b * 64 + i + 1) << 6) + m], w[(size_t)((o * 64 + i + 1) << 6) + m], a1);
        a2 = fmaf(xh[(size_t)((b * 64 + i + 2) << 6) + m], w[(size_t)((o * 64 + i + 2) << 6) + m], a2);
        a3 = fmaf(xh[(size_t)((b * 64 + i + 3) << 6) + m], w[(size_t)((o * 64 + i + 3) << 6) + m], a3);
    }
    lowT[(size_t)m * ROWS + b * 64 + o] = ((a0 + a1) + (a2 + a3)) * (1.0f / (float)N_FFT);
}

// Step C: out[r][n] = sum_m lowT[m][r]*casB[m][n], using half symmetry:
//   out[r][n]      = Se + So
//   out[r][n+8192] = Se - So   (Se: even m, So: odd m; n < 8192)
// grid 1024 = 8 rb * 128 nb; block 256 = 16 rq * 16 nq; per-thread 8r x 4n x 2.
// Both operands global->registers (L1/L2-resident, dup addrs merge).
__global__ __launch_bounds__(256) void kC(const float* __restrict__ lowT,
                                          const float* __restrict__ casB,
                                          float* __restrict__ out) {
    const int nb = blockIdx.x & 127;
    const int rb = blockIdx.x >> 7;
    const int rowbase = rb << 7;
    const int n0 = nb << 6;

    const int t  = threadIdx.x;
    const int rq = t >> 4;            // rows rq*8 .. +7
    const int nq = t & 15;            // n = n0 + nq*4 .. +3

    float se[8][4], so[8][4];
#pragma unroll
    for (int j = 0; j < 8; ++j)
#pragma unroll
        for (int q = 0; q < 4; ++q) { se[j][q] = 0.f; so[j][q] = 0.f; }

    const float* lp = lowT + rowbase + rq * 8;   // + m*1024
    const float* cp = casB + n0 + nq * 4;        // + m*8192

#pragma unroll 4
    for (int m = 0; m < 64; m += 2) {
        const float4 le0 = *reinterpret_cast<const float4*>(lp + (size_t)m * ROWS);
        const float4 le1 = *reinterpret_cast<const float4*>(lp + (size_t)m * ROWS + 4);
        const float4 ce  = *reinterpret_cast<const float4*>(cp + (size_t)m * 8192);
        const float4 lo0 = *reinterpret_cast<const float4*>(lp + (size_t)(m + 1) * ROWS);
        const float4 lo1 = *reinterpret_cast<const float4*>(lp + (size_t)(m + 1) * ROWS + 4);
        const float4 co  = *reinterpret_cast<const float4*>(cp + (size_t)(m + 1) * 8192);
        const float lev[8] = {le0.x, le0.y, le0.z, le0.w, le1.x, le1.y, le1.z, le1.w};
        const float lov[8] = {lo0.x, lo0.y, lo0.z, lo0.w, lo1.x, lo1.y, lo1.z, lo1.w};
        const float cev[4] = {ce.x, ce.y, ce.z, ce.w};
        const float cov[4] = {co.x, co.y, co.z, co.w};
#pragma unroll
        for (int j = 0; j < 8; ++j)
#pragma unroll
            for (int q = 0; q < 4; ++q) {
                se[j][q] = fmaf(lev[j], cev[q], se[j][q]);
                so[j][q] = fmaf(lov[j], cov[q], so[j][q]);
            }
    }

#pragma unroll
    for (int j = 0; j < 8; ++j) {
        const size_t row = (size_t)rowbase + rq * 8 + j;
        *reinterpret_cast<float4*>(&out[row * N_FFT + n0 + nq * 4]) =
            make_float4(se[j][0] + so[j][0], se[j][1] + so[j][1],
                        se[j][2] + so[j][2], se[j][3] + so[j][3]);
        *reinterpret_cast<float4*>(&out[row * N_FFT + 8192 + n0 + nq * 4]) =
            make_float4(se[j][0] - so[j][0], se[j][1] - so[j][1],
                        se[j][2] - so[j][2], se[j][3] - so[j][3]);
    }
}

extern "C" void kernel_launch(void* const* d_in, const int* in_sizes, int n_in,
                              void* d_out, int out_size, void* d_ws, size_t ws_size,
                              hipStream_t stream) {
    const float* x = (const float*)d_in[0];
    const float* w = (const float*)d_in[1];
    float* out = (float*)d_out;
    float* ws  = (float*)d_ws;

    // floats: castab@0[16384] casA@16384[2^20] casB@1064960[2^19]
    //         partial@1589248[KS*65536] xh[65536] lowT[65536]
    const size_t need128 = ((size_t)1589248 + (size_t)128 * 65536 + 2 * 65536) * 4;
    const int KS = (ws_size >= need128) ? 128 : 64;
    const int krange = N_FFT / KS;

    float* castab  = ws;
    float* casA    = ws + 16384;
    float* casB    = ws + 1064960;
    float* partial = ws + 1589248;
    float* xh      = partial + (size_t)KS * 65536;
    float* lowT    = xh + 65536;

    k_tab<<<64, 256, 0, stream>>>(castab);
    k_fill<<<6144, 256, 0, stream>>>(castab, casA, casB);
    kA<<<8 * KS, 128, 0, stream>>>(x, casA, partial, krange);
    kR<<<256, 256, 0, stream>>>(partial, xh, KS);
    kB<<<256, 256, 0, stream>>>(xh, w, lowT);
    kC<<<1024, 256, 0, stream>>>(lowT, casB, out);
}

// Round 5
// 101.975 us; speedup vs baseline: 1.0858x; 1.0114x over previous
//
#include <hip/hip_runtime.h>
#include <math.h>

#define N_FFT 16384
#define ROWS 1024    // B*Cin = B*Cout = 16*64
#define HALF 8192
#define KS 128       // k-splits of the 8192 half-space
#define KRANGE 64    // k per block (half-space)

// ---------------- ws layout (float offsets) ----------------
// castab @0 [16384]; casAp @16384 [8192*64] (perm cols: c<32 -> m=2c, else m=2(c-32)+1)
// casB @540672 [64*8192]; partial @1064960 [KS*65536]; xh @9453568 [65536]; lowT @9519104 [65536]

__global__ __launch_bounds__(256) void k_tab(float* __restrict__ castab) {
    int i = blockIdx.x * 256 + threadIdx.x;
    if (i < N_FFT) {
        double ang = 6.283185307179586476925287 * (double)i / (double)N_FFT;
        castab[i] = (float)(cos(ang) + sin(ang));
    }
}

__global__ __launch_bounds__(256) void k_fill(const float* __restrict__ castab,
                                              float* __restrict__ casAp,
                                              float* __restrict__ casB) {
    int tid = blockIdx.x * 256 + threadIdx.x;    // 0 .. 2^20-1
    if (tid < (1 << 19)) {
        int n = tid >> 6, c = tid & 63;
        int m = (c < 32) ? (2 * c) : (2 * (c - 32) + 1);
        casAp[tid] = castab[(n * m) & (N_FFT - 1)];
    } else {
        int t2 = tid - (1 << 19);                // 0 .. 2^19-1
        int m = t2 >> 13, n = t2 & (HALF - 1);
        casB[t2] = castab[(m * n) & (N_FFT - 1)];
    }
}

// Step A (half-symmetric): for n<8192,
//   partial[ks][r][c] = sum_{n in split} (x[r][n] + s*x[r][n+8192]) * casAp[n][c],
//   s=+1 for even-m cols (c<32), -1 for odd-m cols.
// grid 1024 = 8 rb * 128 ks; block 256 = 64 rq * 4 cq; tile 128r x 64c;
// per-thread 2r x 16c. cas: LDS staged ONCE (16 KB). x: global->reg ping-pong.
__global__ __launch_bounds__(256) void kA(const float* __restrict__ x,
                                          const float* __restrict__ casAp,
                                          float* __restrict__ partial) {
    const int rb = blockIdx.x & 7;
    const int ks = blockIdx.x >> 3;
    const int rowbase = rb << 7;
    const int kbase = ks * KRANGE;

    __shared__ float cs[KRANGE * 64];   // [k][c]

    const int t  = threadIdx.x;
    const int rq = t >> 2;              // rows rowbase + rq*2 + {0,1}
    const int cq = t & 3;               // c = cq*16 .. +15 (pure even or pure odd m)
    const float s = (cq < 2) ? 1.0f : -1.0f;

    {   // stage casAp[kbase..+63][0..63] = 4096 floats, contiguous
        const float4* src = reinterpret_cast<const float4*>(casAp + ((size_t)kbase << 6));
        float4* dst = reinterpret_cast<float4*>(cs);
#pragma unroll
        for (int it = 0; it < 4; ++it) dst[it * 256 + t] = src[it * 256 + t];
    }
    __syncthreads();

    float acc0[16], acc1[16];
#pragma unroll
    for (int q = 0; q < 16; ++q) { acc0[q] = 0.f; acc1[q] = 0.f; }

    const float* xp0 = x + (size_t)(rowbase + rq * 2) * N_FFT + kbase;
    const float* xp1 = xp0 + N_FFT;

#define LOADG(A0, A1, B0, B1, G)                                            \
    A0 = *reinterpret_cast<const float4*>(xp0 + (G) * 4);                   \
    A1 = *reinterpret_cast<const float4*>(xp1 + (G) * 4);                   \
    B0 = *reinterpret_cast<const float4*>(xp0 + HALF + (G) * 4);            \
    B1 = *reinterpret_cast<const float4*>(xp1 + HALF + (G) * 4);

#define COMPG(A0, A1, B0, B1, G)                                            \
    _Pragma("unroll")                                                       \
    for (int u = 0; u < 4; ++u) {                                           \
        const float xa0 = reinterpret_cast<const float*>(&A0)[u];           \
        const float xa1 = reinterpret_cast<const float*>(&A1)[u];           \
        const float xb0 = reinterpret_cast<const float*>(&B0)[u];           \
        const float xb1 = reinterpret_cast<const float*>(&B1)[u];           \
        const float x0 = fmaf(s, xb0, xa0);                                 \
        const float x1 = fmaf(s, xb1, xa1);                                 \
        const float* cr = &cs[((G) * 4 + u) * 64 + cq * 16];                \
        const float4 c0 = *reinterpret_cast<const float4*>(cr);             \
        const float4 c1 = *reinterpret_cast<const float4*>(cr + 4);         \
        const float4 c2 = *reinterpret_cast<const float4*>(cr + 8);         \
        const float4 c3 = *reinterpret_cast<const float4*>(cr + 12);        \
        const float cv[16] = {c0.x, c0.y, c0.z, c0.w, c1.x, c1.y, c1.z,     \
                              c1.w, c2.x, c2.y, c2.z, c2.w, c3.x, c3.y,     \
                              c3.z, c3.w};                                  \
        _Pragma("unroll")                                                   \
        for (int q = 0; q < 16; ++q) {                                      \
            acc0[q] = fmaf(x0, cv[q], acc0[q]);                             \
            acc1[q] = fmaf(x1, cv[q], acc1[q]);                             \
        }                                                                   \
    }

    float4 pA0, pA1, pB0, pB1, qA0, qA1, qB0, qB1;
    LOADG(pA0, pA1, pB0, pB1, 0);
    for (int gg = 0; gg < 8; ++gg) {
        LOADG(qA0, qA1, qB0, qB1, 2 * gg + 1);
        COMPG(pA0, pA1, pB0, pB1, 2 * gg);
        if (gg < 7) { LOADG(pA0, pA1, pB0, pB1, 2 * gg + 2); }
        COMPG(qA0, qA1, qB0, qB1, 2 * gg + 1);
    }
#undef LOADG
#undef COMPG

#pragma unroll
    for (int j = 0; j < 2; ++j) {
        float* p = &partial[((size_t)ks << 16) +
                            (size_t)(rowbase + rq * 2 + j) * 64 + cq * 16];
        const float* a = j ? acc1 : acc0;
        *reinterpret_cast<float4*>(p)      = make_float4(a[0], a[1], a[2], a[3]);
        *reinterpret_cast<float4*>(p + 4)  = make_float4(a[4], a[5], a[6], a[7]);
        *reinterpret_cast<float4*>(p + 8)  = make_float4(a[8], a[9], a[10], a[11]);
        *reinterpret_cast<float4*>(p + 12) = make_float4(a[12], a[13], a[14], a[15]);
    }
}

// reduce KS partials -> xh (un-permuting columns); grid 256 x 256
__global__ __launch_bounds__(256) void kR(const float* __restrict__ partial,
                                          float* __restrict__ xh) {
    const int idx = blockIdx.x * 256 + threadIdx.x;   // 0..65535
    const int r = idx >> 6, c = idx & 63;
    const int m = (c < 32) ? (2 * c) : (2 * (c - 32) + 1);
    float a0 = 0.f, a1 = 0.f, a2 = 0.f, a3 = 0.f;
#pragma unroll 4
    for (int sp = 0; sp < KS; sp += 4) {
        a0 += partial[((size_t)(sp + 0) << 16) + idx];
        a1 += partial[((size_t)(sp + 1) << 16) + idx];
        a2 += partial[((size_t)(sp + 2) << 16) + idx];
        a3 += partial[((size_t)(sp + 3) << 16) + idx];
    }
    xh[(r << 6) + m] = (a0 + a1) + (a2 + a3);
}

// Step B: lowT[m][b*64+o] = (1/N) * sum_i xh[b*64+i][m] * w[(o*64+i)*64+m]
__global__ __launch_bounds__(256) void kB(const float* __restrict__ xh,
                                          const float* __restrict__ w,
                                          float* __restrict__ lowT) {
    const int b  = blockIdx.x >> 4;
    const int og = blockIdx.x & 15;
    const int o  = og * 4 + (threadIdx.x >> 6);
    const int m  = threadIdx.x & 63;
    float a0 = 0.f, a1 = 0.f, a2 = 0.f, a3 = 0.f;
#pragma unroll 4
    for (int i = 0; i < 64; i += 4) {
        a0 = fmaf(xh[(size_t)((b * 64 + i + 0) << 6) + m], w[(size_t)((o * 64 + i + 0) << 6) + m], a0);
        a1 = fmaf(xh[(size_t)((b * 64 + i + 1) << 6) + m], w[(size_t)((o * 64 + i + 1) << 6) + m], a1);
        a2 = fmaf(xh[(size_t)((b * 64 + i + 2) << 6) + m], w[(size_t)((o * 64 + i + 2) << 6) + m], a2);
        a3 = fmaf(xh[(size_t)((b * 64 + i + 3) << 6) + m], w[(size_t)((o * 64 + i + 3) << 6) + m], a3);
    }
    lowT[(size_t)m * ROWS + b * 64 + o] = ((a0 + a1) + (a2 + a3)) * (1.0f / (float)N_FFT);
}

// Step C (half-symmetric): out[r][n] = Se+So, out[r][n+8192] = Se-So (n<8192)
// grid 2048 = 16 rb * 128 nb; block 256 = 16 rq * 16 nq; per-thread 4r x 4n x 2.
__global__ __launch_bounds__(256) void kC(const float* __restrict__ lowT,
                                          const float* __restrict__ casB,
                                          float* __restrict__ out) {
    const int nb = blockIdx.x & 127;
    const int rbb = blockIdx.x >> 7;
    const int rowbase = rbb << 6;
    const int n0 = nb << 6;

    const int t  = threadIdx.x;
    const int rq = t >> 4;            // rows rowbase + rq*4 .. +3
    const int nq = t & 15;            // n = n0 + nq*4 .. +3

    float se[4][4], so[4][4];
#pragma unroll
    for (int j = 0; j < 4; ++j)
#pragma unroll
        for (int q = 0; q < 4; ++q) { se[j][q] = 0.f; so[j][q] = 0.f; }

    const float* lp = lowT + rowbase + rq * 4;   // + m*1024
    const float* cp = casB + n0 + nq * 4;        // + m*8192

#pragma unroll 2
    for (int m = 0; m < 64; m += 2) {
        const float4 le = *reinterpret_cast<const float4*>(lp + (size_t)m * ROWS);
        const float4 lo = *reinterpret_cast<const float4*>(lp + (size_t)(m + 1) * ROWS);
        const float4 ce = *reinterpret_cast<const float4*>(cp + (size_t)m * HALF);
        const float4 co = *reinterpret_cast<const float4*>(cp + (size_t)(m + 1) * HALF);
        const float lev[4] = {le.x, le.y, le.z, le.w};
        const float lov[4] = {lo.x, lo.y, lo.z, lo.w};
        const float cev[4] = {ce.x, ce.y, ce.z, ce.w};
        const float cov[4] = {co.x, co.y, co.z, co.w};
#pragma unroll
        for (int j = 0; j < 4; ++j)
#pragma unroll
            for (int q = 0; q < 4; ++q) {
                se[j][q] = fmaf(lev[j], cev[q], se[j][q]);
                so[j][q] = fmaf(lov[j], cov[q], so[j][q]);
            }
    }

#pragma unroll
    for (int j = 0; j < 4; ++j) {
        const size_t row = (size_t)rowbase + rq * 4 + j;
        *reinterpret_cast<float4*>(&out[row * N_FFT + n0 + nq * 4]) =
            make_float4(se[j][0] + so[j][0], se[j][1] + so[j][1],
                        se[j][2] + so[j][2], se[j][3] + so[j][3]);
        *reinterpret_cast<float4*>(&out[row * N_FFT + HALF + n0 + nq * 4]) =
            make_float4(se[j][0] - so[j][0], se[j][1] - so[j][1],
                        se[j][2] - so[j][2], se[j][3] - so[j][3]);
    }
}

extern "C" void kernel_launch(void* const* d_in, const int* in_sizes, int n_in,
                              void* d_out, int out_size, void* d_ws, size_t ws_size,
                              hipStream_t stream) {
    const float* x = (const float*)d_in[0];
    const float* w = (const float*)d_in[1];
    float* out = (float*)d_out;
    float* ws  = (float*)d_ws;

    float* castab  = ws;
    float* casAp   = ws + 16384;
    float* casB    = ws + 540672;
    float* partial = ws + 1064960;
    float* xh      = ws + 9453568;
    float* lowT    = ws + 9519104;

    k_tab<<<64, 256, 0, stream>>>(castab);
    k_fill<<<4096, 256, 0, stream>>>(castab, casAp, casB);
    kA<<<1024, 256, 0, stream>>>(x, casAp, partial);
    kR<<<256, 256, 0, stream>>>(partial, xh);
    kB<<<256, 256, 0, stream>>>(xh, w, lowT);
    kC<<<2048, 256, 0, stream>>>(lowT, casB, out);
}